// Round 6
// baseline (737.670 us; speedup 1.0000x reference)
//
#include <hip/hip_runtime.h>

typedef unsigned short u16;
typedef __attribute__((ext_vector_type(8))) short short8;
typedef __attribute__((ext_vector_type(4))) float f32x4;
typedef __attribute__((ext_vector_type(4))) unsigned short u16x4;

__device__ __forceinline__ float bf2f(u16 u){
  union { unsigned int i; float f; } x; x.i = ((unsigned int)u) << 16; return x.f;
}
__device__ __forceinline__ u16 f2bf(float f){
  union { float f; unsigned int i; } x; x.f = f;
  return (u16)((x.i + 0x7fffu + ((x.i >> 16) & 1u)) >> 16);
}
__device__ __forceinline__ void async16(const void* g, void* s){
  __builtin_amdgcn_global_load_lds((const __attribute__((address_space(1))) void*)g,
                                   (__attribute__((address_space(3))) void*)s, 16, 0, 0);
}

// ---------------- elementwise bf16-cast kernels ----------------
__global__ __launch_bounds__(256) void k_split2(const float* __restrict__ s1, u16* __restrict__ d1,
                                                const float* __restrict__ s2, u16* __restrict__ d2){
  long i = ((long)blockIdx.x * 256 + threadIdx.x) * 4;
  f32x4 v1 = *(const f32x4*)(s1 + i);
  f32x4 v2 = *(const f32x4*)(s2 + i);
  u16x4 h1, h2;
  #pragma unroll
  for (int j=0;j<4;j++){ h1[j] = f2bf(v1[j]); h2[j] = f2bf(v2[j]); }
  *(u16x4*)(d1+i) = h1;
  *(u16x4*)(d2+i) = h2;
}

__global__ __launch_bounds__(256) void k_addpe(const float* __restrict__ x, const float* __restrict__ pe,
                                               u16* __restrict__ d){
  long i = ((long)blockIdx.x * 256 + threadIdx.x) * 4;
  f32x4 xv = *(const f32x4*)(x + i);
  f32x4 pv = *(const f32x4*)(pe + (i & 1048575));
  u16x4 hh;
  #pragma unroll
  for (int j=0;j<4;j++) hh[j] = f2bf(xv[j]+pv[j]);
  *(u16x4*)(d+i) = hh;
}

// ---------------- 64x64 tiled transpose, (B,L,D)->(B,D,L) ----------------
__global__ __launch_bounds__(256) void k_transpose(const u16* __restrict__ in, u16* __restrict__ outp){
  __shared__ u16 tile[64][68];
  const long b = blockIdx.z;
  const int d0 = blockIdx.x * 64, l0 = blockIdx.y * 64;
  const long ibase = b * 1048576l;
  const int t = threadIdx.x;
  const int cr = t >> 4;
  const int cc = (t & 15) * 4;
  #pragma unroll
  for (int rr=0; rr<4; rr++){
    int row = cr + rr*16;
    u16x4 v = *(const u16x4*)(in + ibase + (long)(l0+row)*1024 + d0 + cc);
    *(u16x4*)&tile[row][cc] = v;
  }
  __syncthreads();
  #pragma unroll
  for (int rr=0; rr<4; rr++){
    int drow = cr + rr*16;
    u16x4 y;
    y[0] = tile[cc+0][drow];
    y[1] = tile[cc+1][drow];
    y[2] = tile[cc+2][drow];
    y[3] = tile[cc+3][drow];
    *(u16x4*)(outp + ibase + (long)(d0+drow)*1024 + l0 + cc) = y;
  }
}

// ---------------- fused scores+softmax: probs = softmax(h h^T / 32) ----------------
// Grid 256 = 16 batches x 16 row-blocks(64). 512 thr / 8 waves; wave = 64 rows x 128 cols.
// B-panel (full 1024x32 per K-step = 64KB = 4096 16B-units; 8 units/thread) staged
// ring-2 (128 KB); A-frags read from the same panel (A rows subset of B rows).
// Epilogue: in-register row softmax, writes probs fp32 (d_out) + bf16 (pB).
__global__ __launch_bounds__(512, 1) void attn_sm(
    const u16* __restrict__ hB, float* __restrict__ probs, u16* __restrict__ pB)
{
  __shared__ __align__(16) u16 sm[65536];   // 2 bufs x (1024 rows x 32 cols) bf16 = 2 x 64KB
  const int t = threadIdx.x;
  const int w = t >> 6, lane = t & 63;
  const int fr = lane & 15, fs = lane >> 4;

  // XCD chunk swizzle (bijective, 256 blocks): 32 consecutive ids (2 batches) per XCD
  const int p = blockIdx.x;
  const int id = (p & 7) * 32 + (p >> 3);
  const long bz = id >> 4;
  const int brow = (id & 15) << 6;

  const u16* hb = hB + bz * 1048576l;

  // staging: 8 x 16B units per thread (u = c*512 + t, c=0..7 -> rows 0..1023).
  // pre-swizzled global source, linear LDS dest (wave-uniform base + lane*16B).
  const u16* gsrc[8];
  int gdst[8];
  #pragma unroll
  for (int c=0;c<8;c++){
    int u = c*512 + t;
    int row = u >> 2;
    int slot = (u & 3) ^ ((row >> 1) & 3);
    gsrc[c] = hb + (long)row*1024 + slot*8;
    gdst[c] = c*4096 + w*512;       // + implicit lane*16B
  }

  // fragment read offsets (u16 units, swizzled) — same convention as gemm8
  int offA[4], offB[8];
  #pragma unroll
  for (int i=0;i<4;i++){
    int x = i*16 + fr;
    offA[i] = (brow + x)*32 + (fs ^ (((brow + x)>>1)&3))*8;
  }
  #pragma unroll
  for (int j=0;j<8;j++){
    int x = w*128 + j*16 + fr;
    offB[j] = x*32 + (fs ^ ((x>>1)&3))*8;
  }

  f32x4 acc[4][8];
  #pragma unroll
  for (int i=0;i<4;i++)
    #pragma unroll
    for (int j=0;j<8;j++) acc[i][j] = (f32x4){0.f,0.f,0.f,0.f};

  // prologue: stage K-tile 0 into buf0
  #pragma unroll
  for (int c=0;c<8;c++) async16(gsrc[c], sm + gdst[c]);
  asm volatile("s_waitcnt vmcnt(0)" ::: "memory");
  __builtin_amdgcn_s_barrier();
  __builtin_amdgcn_sched_barrier(0);

#define ATT_BODY(BUF)                                                          \
    short8 aF[4], bF[8];                                                       \
    _Pragma("unroll")                                                          \
    for (int i=0;i<4;i++) aF[i] = *(const short8*)((BUF) + offA[i]);           \
    _Pragma("unroll")                                                          \
    for (int j=0;j<8;j++) bF[j] = *(const short8*)((BUF) + offB[j]);           \
    __builtin_amdgcn_s_setprio(1);                                             \
    _Pragma("unroll")                                                          \
    for (int i=0;i<4;i++)                                                      \
      _Pragma("unroll")                                                        \
      for (int j=0;j<8;j++)                                                    \
        acc[i][j] = __builtin_amdgcn_mfma_f32_16x16x32_bf16(aF[i], bF[j], acc[i][j], 0,0,0); \
    __builtin_amdgcn_s_setprio(0);

  for (int kt = 0; kt < 31; ++kt){
    const u16* buf = sm + (kt & 1)*32768;
    u16* stg = sm + ((kt + 1) & 1)*32768;
    const int ko = (kt + 1)*32;
    #pragma unroll
    for (int c=0;c<8;c++) async16(gsrc[c] + ko, stg + gdst[c]);
    ATT_BODY(buf)
    asm volatile("s_waitcnt vmcnt(0)" ::: "memory");  // tile kt+1 resident
    __builtin_amdgcn_s_barrier();
    __builtin_amdgcn_sched_barrier(0);
  }
  {
    const u16* buf = sm + 32768;   // kt=31 -> buf1
    ATT_BODY(buf)
  }
#undef ATT_BODY

  // ---- in-register row softmax over scaled scores acc/32 ----
  float* red = (float*)sm;          // aliases buf0 (last body read buf1 only): 64 rows x 8 waves
  const float SC = 0.03125f;

  float mx[4][4];
  #pragma unroll
  for (int i=0;i<4;i++)
    #pragma unroll
    for (int q=0;q<4;q++){
      float m = acc[i][0][q];
      #pragma unroll
      for (int j=1;j<8;j++) m = fmaxf(m, acc[i][j][q]);
      #pragma unroll
      for (int d=1; d<16; d<<=1) m = fmaxf(m, __shfl_xor(m, d));
      mx[i][q] = m;
    }
  if (fr == 0){
    #pragma unroll
    for (int i=0;i<4;i++)
      #pragma unroll
      for (int q=0;q<4;q++) red[(i*16 + fs*4 + q)*8 + w] = mx[i][q];
  }
  __syncthreads();
  float M[4][4];
  #pragma unroll
  for (int i=0;i<4;i++)
    #pragma unroll
    for (int q=0;q<4;q++){
      const int row = i*16 + fs*4 + q;
      f32x4 a = *(const f32x4*)&red[row*8];
      f32x4 b = *(const f32x4*)&red[row*8+4];
      M[i][q] = fmaxf(fmaxf(fmaxf(a[0],a[1]),fmaxf(a[2],a[3])),
                      fmaxf(fmaxf(b[0],b[1]),fmaxf(b[2],b[3])));
    }
  float sum[4][4];
  #pragma unroll
  for (int i=0;i<4;i++)
    #pragma unroll
    for (int q=0;q<4;q++){
      float s = 0.f;
      #pragma unroll
      for (int j=0;j<8;j++){
        float e = expf((acc[i][j][q] - M[i][q]) * SC);
        acc[i][j][q] = e;
        s += e;
      }
      #pragma unroll
      for (int d=1; d<16; d<<=1) s += __shfl_xor(s, d);
      sum[i][q] = s;
    }
  __syncthreads();                  // all M-reads done before red overwrite
  if (fr == 0){
    #pragma unroll
    for (int i=0;i<4;i++)
      #pragma unroll
      for (int q=0;q<4;q++) red[(i*16 + fs*4 + q)*8 + w] = sum[i][q];
  }
  __syncthreads();
  float inv[4][4];
  #pragma unroll
  for (int i=0;i<4;i++)
    #pragma unroll
    for (int q=0;q<4;q++){
      const int row = i*16 + fs*4 + q;
      f32x4 a = *(const f32x4*)&red[row*8];
      f32x4 b = *(const f32x4*)&red[row*8+4];
      inv[i][q] = 1.0f / (a[0]+a[1]+a[2]+a[3]+b[0]+b[1]+b[2]+b[3]);
    }

  // ---- stores: probs fp32 (d_out) + bf16 (pB) ----
  const long obase = bz * 1048576l;
  #pragma unroll
  for (int i=0;i<4;i++)
    #pragma unroll
    for (int q=0;q<4;q++){
      const long rbase = obase + (long)(brow + i*16 + fs*4 + q)*1024;
      const float iv = inv[i][q];
      #pragma unroll
      for (int j=0;j<8;j++){
        const int col = w*128 + j*16 + fr;
        const float pv = acc[i][j][q] * iv;
        probs[rbase + col] = pv;
        pB[rbase + col] = f2bf(pv);
      }
    }
}

// ---------------- 256x256 8-wave deep-pipelined bf16 GEMM, C = A * B^T ----------------
// BK=32, 4-buffer LDS ring (128 KB), counted vmcnt(8).
// MODE 1: bf16 acc ; MODE 2: relu(acc+bias)->bf16 ; MODE 3: acc+bias+res(bf16) -> f32
template<int MODE>
__global__ __launch_bounds__(512, 2) void gemm8(
    const u16* __restrict__ aB, const u16* __restrict__ bB,
    int per, long sA, long sB, long sC,
    int lda, int ldb, int ldc,
    float scale, const float* __restrict__ bias,
    const u16* __restrict__ res,
    float* __restrict__ cF, u16* __restrict__ cB)
{
  __shared__ __align__(16) u16 sm[65536];
  const int t = threadIdx.x;
  const int w = t >> 6, lane = t & 63;
  const int wm = w >> 2, wn = w & 3;
  const int fr = lane & 15, fs = lane >> 4;

  const int p = blockIdx.x;
  const int chunk = gridDim.x >> 3;
  const int id = (p & 7) * chunk + (p >> 3);
  const long bz = id / per;
  const int rem = id % per;
  const int m0 = (rem >> 2) << 8, n0 = (rem & 3) << 8;

  const u16* a = aB + bz * sA;
  const u16* b = bB + bz * sB;

  const int urow = t >> 2;
  const int col8 = ((t & 3) ^ ((t >> 3) & 3)) * 8;
  const u16* gA0 = a + (long)(m0 + urow) * lda + col8;
  const u16* gA1 = a + (long)(m0 + 128 + urow) * lda + col8;
  const u16* gB0 = b + (long)(n0 + urow) * ldb + col8;
  const u16* gB1 = b + (long)(n0 + 128 + urow) * ldb + col8;
  u16* dA0 = sm + (w << 9);
  u16* dA1 = sm + 4096 + (w << 9);
  u16* dB0 = sm + 8192 + (w << 9);
  u16* dB1 = sm + 12288 + (w << 9);

  int offA[8], offB[4];
  #pragma unroll
  for (int i=0;i<8;i++){
    int row = wm*128 + i*16 + fr;
    int sl = fs ^ ((row >> 1) & 3);
    offA[i] = row*32 + sl*8;
  }
  #pragma unroll
  for (int j=0;j<4;j++){
    int row = wn*64 + j*16 + fr;
    int sl = fs ^ ((row >> 1) & 3);
    offB[j] = 8192 + row*32 + sl*8;
  }

  f32x4 acc[8][4];
  #pragma unroll
  for (int i=0;i<8;i++)
    #pragma unroll
    for (int j=0;j<4;j++) acc[i][j] = (f32x4){0.f,0.f,0.f,0.f};

  #pragma unroll
  for (int pb=0; pb<3; ++pb){
    const int kb = pb*32, sb = pb*16384;
    async16(gA0+kb, dA0+sb); async16(gA1+kb, dA1+sb);
    async16(gB0+kb, dB0+sb); async16(gB1+kb, dB1+sb);
  }
  gA0 += 96; gA1 += 96; gB0 += 96; gB1 += 96;
  asm volatile("s_waitcnt vmcnt(8)" ::: "memory");
  __builtin_amdgcn_s_barrier();
  __builtin_amdgcn_sched_barrier(0);

#define KT_BODY(SMB)                                                           \
    short8 aF[8], bF[4];                                                       \
    _Pragma("unroll")                                                          \
    for (int i=0;i<8;i++) aF[i] = *(const short8*)((SMB) + offA[i]);           \
    _Pragma("unroll")                                                          \
    for (int j=0;j<4;j++) bF[j] = *(const short8*)((SMB) + offB[j]);           \
    __builtin_amdgcn_s_barrier();                                              \
    __builtin_amdgcn_sched_barrier(0);                                         \
    __builtin_amdgcn_s_setprio(1);                                             \
    _Pragma("unroll")                                                          \
    for (int i=0;i<8;i++){                                                     \
      acc[i][0] = __builtin_amdgcn_mfma_f32_16x16x32_bf16(aF[i], bF[0], acc[i][0], 0,0,0); \
      acc[i][1] = __builtin_amdgcn_mfma_f32_16x16x32_bf16(aF[i], bF[1], acc[i][1], 0,0,0); \
    }                                                                          \
    _Pragma("unroll")                                                          \
    for (int i=0;i<8;i++){                                                     \
      acc[i][2] = __builtin_amdgcn_mfma_f32_16x16x32_bf16(aF[i], bF[2], acc[i][2], 0,0,0); \
      acc[i][3] = __builtin_amdgcn_mfma_f32_16x16x32_bf16(aF[i], bF[3], acc[i][3], 0,0,0); \
    }                                                                          \
    __builtin_amdgcn_s_setprio(0);

  for (int kt = 0; kt < 29; ++kt){
    const u16* smb = sm + (kt & 3)*16384;
    const int sb = ((kt + 3) & 3)*16384;
    async16(gA0, dA0+sb); async16(gA1, dA1+sb);
    async16(gB0, dB0+sb); async16(gB1, dB1+sb);
    gA0 += 32; gA1 += 32; gB0 += 32; gB1 += 32;
    KT_BODY(smb)
    asm volatile("s_waitcnt vmcnt(8)" ::: "memory");
    __builtin_amdgcn_s_barrier();
    __builtin_amdgcn_sched_barrier(0);
  }
  {
    const u16* smb = sm + (29 & 3)*16384;
    KT_BODY(smb)
    asm volatile("s_waitcnt vmcnt(4)" ::: "memory");
    __builtin_amdgcn_s_barrier();
    __builtin_amdgcn_sched_barrier(0);
  }
  {
    const u16* smb = sm + (30 & 3)*16384;
    KT_BODY(smb)
    asm volatile("s_waitcnt vmcnt(0)" ::: "memory");
    __builtin_amdgcn_s_barrier();
    __builtin_amdgcn_sched_barrier(0);
  }
  {
    const u16* smb = sm + (31 & 3)*16384;
    KT_BODY(smb)
  }
#undef KT_BODY

  const long cBase = bz * sC;
  const int rb = m0 + wm*128 + fs*4;
  const int cb = n0 + wn*64 + fr;
  #pragma unroll
  for (int j=0;j<4;j++){
    const int c = cb + j*16;
    float bv = 0.f;
    if constexpr (MODE == 2 || MODE == 3) bv = bias[c];
    #pragma unroll
    for (int i=0;i<8;i++){
      #pragma unroll
      for (int q=0;q<4;q++){
        const int r = rb + i*16 + q;
        const long idx = cBase + (long)r*ldc + c;
        float v = acc[i][j][q];
        if constexpr (MODE == 1){
          cB[idx] = f2bf(v);
        } else if constexpr (MODE == 2){
          cB[idx] = f2bf(fmaxf(v + bv, 0.f));
        } else {
          cF[idx] = v + bv + bf2f(res[idx]);
        }
      }
    }
  }
}

// ---------------- layernorm over 1024, writes h bf16 ----------------
__global__ __launch_bounds__(256) void k_ln(const float* __restrict__ r,
                                            const float* __restrict__ g, const float* __restrict__ b,
                                            u16* __restrict__ h){
  const long row = blockIdx.x;
  const float* rr = r + row * 1024;
  const int t = threadIdx.x, w = t >> 6, lane = t & 63;
  __shared__ float rA[4], rB[4];
  f32x4 v = *(const f32x4*)(rr + t*4);
  float s = v[0]+v[1]+v[2]+v[3];
  #pragma unroll
  for (int off=32; off; off>>=1) s += __shfl_xor(s, off);
  if (lane==0) rA[w] = s;
  __syncthreads();
  const float mu = (rA[0]+rA[1]+rA[2]+rA[3]) * (1.0f/1024.0f);
  float sq = 0.f;
  #pragma unroll
  for (int j=0;j<4;j++){ float d = v[j]-mu; sq += d*d; }
  #pragma unroll
  for (int off=32; off; off>>=1) sq += __shfl_xor(sq, off);
  if (lane==0) rB[w] = sq;
  __syncthreads();
  const float var = (rB[0]+rB[1]+rB[2]+rB[3]) * (1.0f/1024.0f);
  const float inv = rsqrtf(var + 1e-5f);
  u16x4 hh;
  #pragma unroll
  for (int j=0;j<4;j++){
    int d = t*4+j;
    hh[j] = f2bf((v[j]-mu)*inv*g[d] + b[d]);
  }
  *(u16x4*)(h + row*1024 + t*4) = hh;
}

// ---------------- final head ----------------
__global__ __launch_bounds__(256) void k_final1(const u16* __restrict__ h,
                                                const float* __restrict__ fw, const float* __restrict__ fb,
                                                float* __restrict__ z){
  const int row = blockIdx.x*4 + (threadIdx.x>>6);
  const int lane = threadIdx.x & 63;
  const long base = (long)row * 1024;
  const int d0 = lane * 16;
  float s = 0.f;
  #pragma unroll
  for (int j=0;j<16;j++){
    int d = d0 + j;
    s += bf2f(h[base+d]) * fw[d];
  }
  #pragma unroll
  for (int off=32; off; off>>=1) s += __shfl_xor(s, off);
  if (lane==0) z[row] = s + fb[0];
}

__global__ __launch_bounds__(256) void k_final2(const float* __restrict__ z,
                                                const float* __restrict__ fw, const float* __restrict__ fb,
                                                float* __restrict__ out){
  const int idx = blockIdx.x*4 + (threadIdx.x>>6);
  const int lane = threadIdx.x & 63;
  const int b = idx / 24, o = idx % 24;
  float s = 0.f;
  #pragma unroll
  for (int j=0;j<16;j++){
    int li = lane + j*64;
    s += z[b*1024 + li] * fw[o*1024 + li];
  }
  #pragma unroll
  for (int off=32; off; off>>=1) s += __shfl_xor(s, off);
  if (lane==0) out[idx] = s + fb[o];
}

// ---------------- launch ----------------
extern "C" void kernel_launch(void* const* d_in, const int* in_sizes, int n_in,
                              void* d_out, int out_size, void* d_ws, size_t ws_size,
                              hipStream_t stream){
  const float* x   = (const float*)d_in[0];
  const float* pe  = (const float*)d_in[1];
  const float* w1  = (const float*)d_in[2];
  const float* b1  = (const float*)d_in[3];
  const float* w2  = (const float*)d_in[4];
  const float* b2  = (const float*)d_in[5];
  const float* lng = (const float*)d_in[6];
  const float* lnb = (const float*)d_in[7];
  const float* fcw = (const float*)d_in[8];
  const float* fcb = (const float*)d_in[9];
  const float* fw  = (const float*)d_in[10];
  const float* fb  = (const float*)d_in[11];
  float* out  = (float*)d_out;
  float* attn = out + 384;                 // (3,16,1024,1024) fp32

  char* ws = (char*)d_ws;
  const long BB = 32l*1024*1024;
  u16* hB = (u16*)(ws + 0*BB);
  u16* tB = (u16*)(ws + 1*BB);             // h^T
  u16* cB = (u16*)(ws + 2*BB);             // ctx
  u16* pB = (u16*)(ws + 3*BB);             // probs (reused as y1)
  float* rf = (float*)(ws + 4*BB);         // pre-LN f32 (64MB)
  u16* w1B = (u16*)(ws + 6*BB);
  u16* w2B = w1B + 3l*1024*1024;
  float* z = (float*)(w2B + 3l*1024*1024);

  const long M1 = 1024l*1024;

  k_split2<<<3072, 256, 0, stream>>>(w1, w1B, w2, w2B);
  k_addpe<<<16384, 256, 0, stream>>>(x, pe, hB);
  k_transpose<<<dim3(16,16,16), 256, 0, stream>>>(hB, tB);

  for (int l = 0; l < 3; l++){
    float* sc = attn + (long)l*16*M1;
    // probs = softmax(h h^T / 32) -> d_out (fp32) + pB (bf16), fused
    attn_sm<<<256, 512, 0, stream>>>(hB, sc, pB);
    // ctx = P h   (B = h^T, K-contig)
    gemm8<1><<<256, 512, 0, stream>>>(pB, tB, 16, M1,M1,M1, 1024,1024,1024,
        1.f, nullptr, nullptr, nullptr, cB);
    // y1 = relu(ctx w1^T + b1)
    gemm8<2><<<256, 512, 0, stream>>>(cB, w1B+l*M1, 256, 0,0,0, 1024,1024,1024,
        1.f, b1+l*1024, nullptr, nullptr, pB);
    // rf = y1 w2^T + b2 + ctx
    gemm8<3><<<256, 512, 0, stream>>>(pB, w2B+l*M1, 256, 0,0,0, 1024,1024,1024,
        1.f, b2+l*1024, cB, rf, nullptr);
    // h = LN(rf)*g + b
    k_ln<<<16384, 256, 0, stream>>>(rf, lng+l*1024, lnb+l*1024, hB);
    if (l < 2) k_transpose<<<dim3(16,16,16), 256, 0, stream>>>(hB, tB);
  }

  k_final1<<<4096, 256, 0, stream>>>(hB, fcw, fcb, z);
  k_final2<<<96, 256, 0, stream>>>(z, fw, fb, out);
}

// Round 7
// 725.679 us; speedup vs baseline: 1.0165x; 1.0165x over previous
//
#include <hip/hip_runtime.h>

typedef unsigned short u16;
typedef __attribute__((ext_vector_type(8))) short short8;
typedef __attribute__((ext_vector_type(4))) float f32x4;
typedef __attribute__((ext_vector_type(4))) unsigned short u16x4;

__device__ __forceinline__ float bf2f(u16 u){
  union { unsigned int i; float f; } x; x.i = ((unsigned int)u) << 16; return x.f;
}
__device__ __forceinline__ u16 f2bf(float f){
  union { float f; unsigned int i; } x; x.f = f;
  return (u16)((x.i + 0x7fffu + ((x.i >> 16) & 1u)) >> 16);
}
__device__ __forceinline__ void async16(const void* g, void* s){
  __builtin_amdgcn_global_load_lds((const __attribute__((address_space(1))) void*)g,
                                   (__attribute__((address_space(3))) void*)s, 16, 0, 0);
}

// ---------------- elementwise bf16-cast kernels ----------------
__global__ __launch_bounds__(256) void k_split2(const float* __restrict__ s1, u16* __restrict__ d1,
                                                const float* __restrict__ s2, u16* __restrict__ d2){
  long i = ((long)blockIdx.x * 256 + threadIdx.x) * 4;
  f32x4 v1 = *(const f32x4*)(s1 + i);
  f32x4 v2 = *(const f32x4*)(s2 + i);
  u16x4 h1, h2;
  #pragma unroll
  for (int j=0;j<4;j++){ h1[j] = f2bf(v1[j]); h2[j] = f2bf(v2[j]); }
  *(u16x4*)(d1+i) = h1;
  *(u16x4*)(d2+i) = h2;
}

__global__ __launch_bounds__(256) void k_addpe(const float* __restrict__ x, const float* __restrict__ pe,
                                               u16* __restrict__ d){
  long i = ((long)blockIdx.x * 256 + threadIdx.x) * 4;
  f32x4 xv = *(const f32x4*)(x + i);
  f32x4 pv = *(const f32x4*)(pe + (i & 1048575));
  u16x4 hh;
  #pragma unroll
  for (int j=0;j<4;j++) hh[j] = f2bf(xv[j]+pv[j]);
  *(u16x4*)(d+i) = hh;
}

// ---------------- 64x64 tiled transpose, (B,L,D)->(B,D,L) ----------------
__global__ __launch_bounds__(256) void k_transpose(const u16* __restrict__ in, u16* __restrict__ outp){
  __shared__ u16 tile[64][68];
  const long b = blockIdx.z;
  const int d0 = blockIdx.x * 64, l0 = blockIdx.y * 64;
  const long ibase = b * 1048576l;
  const int t = threadIdx.x;
  const int cr = t >> 4;
  const int cc = (t & 15) * 4;
  #pragma unroll
  for (int rr=0; rr<4; rr++){
    int row = cr + rr*16;
    u16x4 v = *(const u16x4*)(in + ibase + (long)(l0+row)*1024 + d0 + cc);
    *(u16x4*)&tile[row][cc] = v;
  }
  __syncthreads();
  #pragma unroll
  for (int rr=0; rr<4; rr++){
    int drow = cr + rr*16;
    u16x4 y;
    y[0] = tile[cc+0][drow];
    y[1] = tile[cc+1][drow];
    y[2] = tile[cc+2][drow];
    y[3] = tile[cc+3][drow];
    *(u16x4*)(outp + ibase + (long)(d0+drow)*1024 + l0 + cc) = y;
  }
}

// ---------------- fused scores+softmax: probs = softmax(h h^T / 32) ----------------
__global__ __launch_bounds__(512, 1) void attn_sm(
    const u16* __restrict__ hB, float* __restrict__ probs, u16* __restrict__ pB)
{
  __shared__ __align__(16) u16 sm[65536];   // 2 bufs x (1024 rows x 32 cols) bf16 = 2 x 64KB
  const int t = threadIdx.x;
  const int w = t >> 6, lane = t & 63;
  const int fr = lane & 15, fs = lane >> 4;

  const int p = blockIdx.x;
  const int id = (p & 7) * 32 + (p >> 3);
  const long bz = id >> 4;
  const int brow = (id & 15) << 6;

  const u16* hb = hB + bz * 1048576l;

  const u16* gsrc[8];
  int gdst[8];
  #pragma unroll
  for (int c=0;c<8;c++){
    int u = c*512 + t;
    int row = u >> 2;
    int slot = (u & 3) ^ ((row >> 1) & 3);
    gsrc[c] = hb + (long)row*1024 + slot*8;
    gdst[c] = c*4096 + w*512;
  }

  int offA[4], offB[8];
  #pragma unroll
  for (int i=0;i<4;i++){
    int x = i*16 + fr;
    offA[i] = (brow + x)*32 + (fs ^ (((brow + x)>>1)&3))*8;
  }
  #pragma unroll
  for (int j=0;j<8;j++){
    int x = w*128 + j*16 + fr;
    offB[j] = x*32 + (fs ^ ((x>>1)&3))*8;
  }

  f32x4 acc[4][8];
  #pragma unroll
  for (int i=0;i<4;i++)
    #pragma unroll
    for (int j=0;j<8;j++) acc[i][j] = (f32x4){0.f,0.f,0.f,0.f};

  #pragma unroll
  for (int c=0;c<8;c++) async16(gsrc[c], sm + gdst[c]);
  asm volatile("s_waitcnt vmcnt(0)" ::: "memory");
  __builtin_amdgcn_s_barrier();
  __builtin_amdgcn_sched_barrier(0);

#define ATT_BODY(BUF)                                                          \
    short8 aF[4], bF[8];                                                       \
    _Pragma("unroll")                                                          \
    for (int i=0;i<4;i++) aF[i] = *(const short8*)((BUF) + offA[i]);           \
    _Pragma("unroll")                                                          \
    for (int j=0;j<8;j++) bF[j] = *(const short8*)((BUF) + offB[j]);           \
    __builtin_amdgcn_s_setprio(1);                                             \
    _Pragma("unroll")                                                          \
    for (int i=0;i<4;i++)                                                      \
      _Pragma("unroll")                                                        \
      for (int j=0;j<8;j++)                                                    \
        acc[i][j] = __builtin_amdgcn_mfma_f32_16x16x32_bf16(aF[i], bF[j], acc[i][j], 0,0,0); \
    __builtin_amdgcn_s_setprio(0);

  for (int kt = 0; kt < 31; ++kt){
    const u16* buf = sm + (kt & 1)*32768;
    u16* stg = sm + ((kt + 1) & 1)*32768;
    const int ko = (kt + 1)*32;
    #pragma unroll
    for (int c=0;c<8;c++) async16(gsrc[c] + ko, stg + gdst[c]);
    ATT_BODY(buf)
    asm volatile("s_waitcnt vmcnt(0)" ::: "memory");
    __builtin_amdgcn_s_barrier();
    __builtin_amdgcn_sched_barrier(0);
  }
  {
    const u16* buf = sm + 32768;
    ATT_BODY(buf)
  }
#undef ATT_BODY

  float* red = (float*)sm;
  const float SC = 0.03125f;

  float mx[4][4];
  #pragma unroll
  for (int i=0;i<4;i++)
    #pragma unroll
    for (int q=0;q<4;q++){
      float m = acc[i][0][q];
      #pragma unroll
      for (int j=1;j<8;j++) m = fmaxf(m, acc[i][j][q]);
      #pragma unroll
      for (int d=1; d<16; d<<=1) m = fmaxf(m, __shfl_xor(m, d));
      mx[i][q] = m;
    }
  if (fr == 0){
    #pragma unroll
    for (int i=0;i<4;i++)
      #pragma unroll
      for (int q=0;q<4;q++) red[(i*16 + fs*4 + q)*8 + w] = mx[i][q];
  }
  __syncthreads();
  float M[4][4];
  #pragma unroll
  for (int i=0;i<4;i++)
    #pragma unroll
    for (int q=0;q<4;q++){
      const int row = i*16 + fs*4 + q;
      f32x4 a = *(const f32x4*)&red[row*8];
      f32x4 b = *(const f32x4*)&red[row*8+4];
      M[i][q] = fmaxf(fmaxf(fmaxf(a[0],a[1]),fmaxf(a[2],a[3])),
                      fmaxf(fmaxf(b[0],b[1]),fmaxf(b[2],b[3])));
    }
  float sum[4][4];
  #pragma unroll
  for (int i=0;i<4;i++)
    #pragma unroll
    for (int q=0;q<4;q++){
      float s = 0.f;
      #pragma unroll
      for (int j=0;j<8;j++){
        float e = expf((acc[i][j][q] - M[i][q]) * SC);
        acc[i][j][q] = e;
        s += e;
      }
      #pragma unroll
      for (int d=1; d<16; d<<=1) s += __shfl_xor(s, d);
      sum[i][q] = s;
    }
  __syncthreads();
  if (fr == 0){
    #pragma unroll
    for (int i=0;i<4;i++)
      #pragma unroll
      for (int q=0;q<4;q++) red[(i*16 + fs*4 + q)*8 + w] = sum[i][q];
  }
  __syncthreads();
  float inv[4][4];
  #pragma unroll
  for (int i=0;i<4;i++)
    #pragma unroll
    for (int q=0;q<4;q++){
      const int row = i*16 + fs*4 + q;
      f32x4 a = *(const f32x4*)&red[row*8];
      f32x4 b = *(const f32x4*)&red[row*8+4];
      inv[i][q] = 1.0f / (a[0]+a[1]+a[2]+a[3]+b[0]+b[1]+b[2]+b[3]);
    }

  const long obase = bz * 1048576l;
  #pragma unroll
  for (int i=0;i<4;i++)
    #pragma unroll
    for (int q=0;q<4;q++){
      const long rbase = obase + (long)(brow + i*16 + fs*4 + q)*1024;
      const float iv = inv[i][q];
      #pragma unroll
      for (int j=0;j<8;j++){
        const int col = w*128 + j*16 + fr;
        const float pv = acc[i][j][q] * iv;
        probs[rbase + col] = pv;
        pB[rbase + col] = f2bf(pv);
      }
    }
}

// ---------------- 256x256 8-wave 2-phase bf16 GEMM, C = A * B^T ----------------
// BK=32, 4-buffer LDS ring (128 KB), counted vmcnt(8) — loads span 3 K-tiles.
// Per K-tile 2 phases: ph1 {aF[0..3]+bF[0..3] reads | A-stage(kt+3) | bar | 16 MFMA i0-3}
//                      ph2 {aF[4..7] reads | B-stage(kt+3) | bar | 16 MFMA i4-7 | vmcnt(8) | bar}
// Bit-identical accumulation order per acc[i][j] vs single-phase version.
// MODE 1: bf16 acc ; MODE 2: relu(acc+bias)->bf16 ; MODE 3: acc+bias+res(bf16) -> f32
template<int MODE>
__global__ __launch_bounds__(512, 2) void gemm8(
    const u16* __restrict__ aB, const u16* __restrict__ bB,
    int per, long sA, long sB, long sC,
    int lda, int ldb, int ldc,
    float scale, const float* __restrict__ bias,
    const u16* __restrict__ res,
    float* __restrict__ cF, u16* __restrict__ cB)
{
  __shared__ __align__(16) u16 sm[65536];
  const int t = threadIdx.x;
  const int w = t >> 6, lane = t & 63;
  const int wm = w >> 2, wn = w & 3;
  const int fr = lane & 15, fs = lane >> 4;

  const int p = blockIdx.x;
  const int chunk = gridDim.x >> 3;
  const int id = (p & 7) * chunk + (p >> 3);
  const long bz = id / per;
  const int rem = id % per;
  const int m0 = (rem >> 2) << 8, n0 = (rem & 3) << 8;

  const u16* a = aB + bz * sA;
  const u16* b = bB + bz * sB;

  const int urow = t >> 2;
  const int col8 = ((t & 3) ^ ((t >> 3) & 3)) * 8;
  const u16* gA0 = a + (long)(m0 + urow) * lda + col8;
  const u16* gA1 = a + (long)(m0 + 128 + urow) * lda + col8;
  const u16* gB0 = b + (long)(n0 + urow) * ldb + col8;
  const u16* gB1 = b + (long)(n0 + 128 + urow) * ldb + col8;
  u16* dA0 = sm + (w << 9);
  u16* dA1 = sm + 4096 + (w << 9);
  u16* dB0 = sm + 8192 + (w << 9);
  u16* dB1 = sm + 12288 + (w << 9);

  int offA[8], offB[4];
  #pragma unroll
  for (int i=0;i<8;i++){
    int row = wm*128 + i*16 + fr;
    int sl = fs ^ ((row >> 1) & 3);
    offA[i] = row*32 + sl*8;
  }
  #pragma unroll
  for (int j=0;j<4;j++){
    int row = wn*64 + j*16 + fr;
    int sl = fs ^ ((row >> 1) & 3);
    offB[j] = 8192 + row*32 + sl*8;
  }

  f32x4 acc[8][4];
  #pragma unroll
  for (int i=0;i<8;i++)
    #pragma unroll
    for (int j=0;j<4;j++) acc[i][j] = (f32x4){0.f,0.f,0.f,0.f};

  #pragma unroll
  for (int pb=0; pb<3; ++pb){
    const int kb = pb*32, sb = pb*16384;
    async16(gA0+kb, dA0+sb); async16(gA1+kb, dA1+sb);
    async16(gB0+kb, dB0+sb); async16(gB1+kb, dB1+sb);
  }
  gA0 += 96; gA1 += 96; gB0 += 96; gB1 += 96;
  asm volatile("s_waitcnt vmcnt(8)" ::: "memory");
  __builtin_amdgcn_s_barrier();
  __builtin_amdgcn_sched_barrier(0);

  // STAGE_A/STAGE_B: empty or the A/B half of the kt+3 stage.
#define KT_BODY2(SMB, STAGE_A, STAGE_B)                                        \
  { short8 aF[8], bF[4];                                                       \
    _Pragma("unroll")                                                          \
    for (int i=0;i<4;i++) aF[i] = *(const short8*)((SMB) + offA[i]);           \
    _Pragma("unroll")                                                          \
    for (int j=0;j<4;j++) bF[j] = *(const short8*)((SMB) + offB[j]);           \
    STAGE_A                                                                    \
    __builtin_amdgcn_sched_barrier(0);                                         \
    __builtin_amdgcn_s_barrier();                                              \
    __builtin_amdgcn_sched_barrier(0);                                         \
    __builtin_amdgcn_s_setprio(1);                                             \
    _Pragma("unroll")                                                          \
    for (int i=0;i<4;i++){                                                     \
      acc[i][0] = __builtin_amdgcn_mfma_f32_16x16x32_bf16(aF[i], bF[0], acc[i][0], 0,0,0); \
      acc[i][1] = __builtin_amdgcn_mfma_f32_16x16x32_bf16(aF[i], bF[1], acc[i][1], 0,0,0); \
      acc[i][2] = __builtin_amdgcn_mfma_f32_16x16x32_bf16(aF[i], bF[2], acc[i][2], 0,0,0); \
      acc[i][3] = __builtin_amdgcn_mfma_f32_16x16x32_bf16(aF[i], bF[3], acc[i][3], 0,0,0); \
    }                                                                          \
    __builtin_amdgcn_s_setprio(0);                                             \
    _Pragma("unroll")                                                          \
    for (int i=4;i<8;i++) aF[i] = *(const short8*)((SMB) + offA[i]);           \
    STAGE_B                                                                    \
    __builtin_amdgcn_sched_barrier(0);                                         \
    __builtin_amdgcn_s_barrier();                                              \
    __builtin_amdgcn_sched_barrier(0);                                         \
    __builtin_amdgcn_s_setprio(1);                                             \
    _Pragma("unroll")                                                          \
    for (int i=4;i<8;i++){                                                     \
      acc[i][0] = __builtin_amdgcn_mfma_f32_16x16x32_bf16(aF[i], bF[0], acc[i][0], 0,0,0); \
      acc[i][1] = __builtin_amdgcn_mfma_f32_16x16x32_bf16(aF[i], bF[1], acc[i][1], 0,0,0); \
      acc[i][2] = __builtin_amdgcn_mfma_f32_16x16x32_bf16(aF[i], bF[2], acc[i][2], 0,0,0); \
      acc[i][3] = __builtin_amdgcn_mfma_f32_16x16x32_bf16(aF[i], bF[3], acc[i][3], 0,0,0); \
    }                                                                          \
    __builtin_amdgcn_s_setprio(0);                                             \
  }

  for (int kt = 0; kt < 29; ++kt){
    const u16* smb = sm + (kt & 3)*16384;
    const int sb = ((kt + 3) & 3)*16384;
    KT_BODY2(smb,
      { async16(gA0, dA0+sb); async16(gA1, dA1+sb); gA0 += 32; gA1 += 32; },
      { async16(gB0, dB0+sb); async16(gB1, dB1+sb); gB0 += 32; gB1 += 32; })
    asm volatile("s_waitcnt vmcnt(8)" ::: "memory");
    __builtin_amdgcn_s_barrier();
    __builtin_amdgcn_sched_barrier(0);
  }
  {
    const u16* smb = sm + (29 & 3)*16384;
    KT_BODY2(smb, {}, {})
    asm volatile("s_waitcnt vmcnt(4)" ::: "memory");
    __builtin_amdgcn_s_barrier();
    __builtin_amdgcn_sched_barrier(0);
  }
  {
    const u16* smb = sm + (30 & 3)*16384;
    KT_BODY2(smb, {}, {})
    asm volatile("s_waitcnt vmcnt(0)" ::: "memory");
    __builtin_amdgcn_s_barrier();
    __builtin_amdgcn_sched_barrier(0);
  }
  {
    const u16* smb = sm + (31 & 3)*16384;
    KT_BODY2(smb, {}, {})
  }
#undef KT_BODY2

  const long cBase = bz * sC;
  const int rb = m0 + wm*128 + fs*4;
  const int cb = n0 + wn*64 + fr;
  #pragma unroll
  for (int j=0;j<4;j++){
    const int c = cb + j*16;
    float bv = 0.f;
    if constexpr (MODE == 2 || MODE == 3) bv = bias[c];
    #pragma unroll
    for (int i=0;i<8;i++){
      #pragma unroll
      for (int q=0;q<4;q++){
        const int r = rb + i*16 + q;
        const long idx = cBase + (long)r*ldc + c;
        float v = acc[i][j][q];
        if constexpr (MODE == 1){
          cB[idx] = f2bf(v);
        } else if constexpr (MODE == 2){
          cB[idx] = f2bf(fmaxf(v + bv, 0.f));
        } else {
          cF[idx] = v + bv + bf2f(res[idx]);
        }
      }
    }
  }
}

// ---------------- layernorm over 1024, writes h bf16 ----------------
__global__ __launch_bounds__(256) void k_ln(const float* __restrict__ r,
                                            const float* __restrict__ g, const float* __restrict__ b,
                                            u16* __restrict__ h){
  const long row = blockIdx.x;
  const float* rr = r + row * 1024;
  const int t = threadIdx.x, w = t >> 6, lane = t & 63;
  __shared__ float rA[4], rB[4];
  f32x4 v = *(const f32x4*)(rr + t*4);
  float s = v[0]+v[1]+v[2]+v[3];
  #pragma unroll
  for (int off=32; off; off>>=1) s += __shfl_xor(s, off);
  if (lane==0) rA[w] = s;
  __syncthreads();
  const float mu = (rA[0]+rA[1]+rA[2]+rA[3]) * (1.0f/1024.0f);
  float sq = 0.f;
  #pragma unroll
  for (int j=0;j<4;j++){ float d = v[j]-mu; sq += d*d; }
  #pragma unroll
  for (int off=32; off; off>>=1) sq += __shfl_xor(sq, off);
  if (lane==0) rB[w] = sq;
  __syncthreads();
  const float var = (rB[0]+rB[1]+rB[2]+rB[3]) * (1.0f/1024.0f);
  const float inv = rsqrtf(var + 1e-5f);
  u16x4 hh;
  #pragma unroll
  for (int j=0;j<4;j++){
    int d = t*4+j;
    hh[j] = f2bf((v[j]-mu)*inv*g[d] + b[d]);
  }
  *(u16x4*)(h + row*1024 + t*4) = hh;
}

// ---------------- final head ----------------
__global__ __launch_bounds__(256) void k_final1(const u16* __restrict__ h,
                                                const float* __restrict__ fw, const float* __restrict__ fb,
                                                float* __restrict__ z){
  const int row = blockIdx.x*4 + (threadIdx.x>>6);
  const int lane = threadIdx.x & 63;
  const long base = (long)row * 1024;
  const int d0 = lane * 16;
  float s = 0.f;
  #pragma unroll
  for (int j=0;j<16;j++){
    int d = d0 + j;
    s += bf2f(h[base+d]) * fw[d];
  }
  #pragma unroll
  for (int off=32; off; off>>=1) s += __shfl_xor(s, off);
  if (lane==0) z[row] = s + fb[0];
}

__global__ __launch_bounds__(256) void k_final2(const float* __restrict__ z,
                                                const float* __restrict__ fw, const float* __restrict__ fb,
                                                float* __restrict__ out){
  const int idx = blockIdx.x*4 + (threadIdx.x>>6);
  const int lane = threadIdx.x & 63;
  const int b = idx / 24, o = idx % 24;
  float s = 0.f;
  #pragma unroll
  for (int j=0;j<16;j++){
    int li = lane + j*64;
    s += z[b*1024 + li] * fw[o*1024 + li];
  }
  #pragma unroll
  for (int off=32; off; off>>=1) s += __shfl_xor(s, off);
  if (lane==0) out[idx] = s + fb[o];
}

// ---------------- launch ----------------
extern "C" void kernel_launch(void* const* d_in, const int* in_sizes, int n_in,
                              void* d_out, int out_size, void* d_ws, size_t ws_size,
                              hipStream_t stream){
  const float* x   = (const float*)d_in[0];
  const float* pe  = (const float*)d_in[1];
  const float* w1  = (const float*)d_in[2];
  const float* b1  = (const float*)d_in[3];
  const float* w2  = (const float*)d_in[4];
  const float* b2  = (const float*)d_in[5];
  const float* lng = (const float*)d_in[6];
  const float* lnb = (const float*)d_in[7];
  const float* fcw = (const float*)d_in[8];
  const float* fcb = (const float*)d_in[9];
  const float* fw  = (const float*)d_in[10];
  const float* fb  = (const float*)d_in[11];
  float* out  = (float*)d_out;
  float* attn = out + 384;                 // (3,16,1024,1024) fp32

  char* ws = (char*)d_ws;
  const long BB = 32l*1024*1024;
  u16* hB = (u16*)(ws + 0*BB);
  u16* tB = (u16*)(ws + 1*BB);             // h^T
  u16* cB = (u16*)(ws + 2*BB);             // ctx
  u16* pB = (u16*)(ws + 3*BB);             // probs (reused as y1)
  float* rf = (float*)(ws + 4*BB);         // pre-LN f32 (64MB)
  u16* w1B = (u16*)(ws + 6*BB);
  u16* w2B = w1B + 3l*1024*1024;
  float* z = (float*)(w2B + 3l*1024*1024);

  const long M1 = 1024l*1024;

  k_split2<<<3072, 256, 0, stream>>>(w1, w1B, w2, w2B);
  k_addpe<<<16384, 256, 0, stream>>>(x, pe, hB);
  k_transpose<<<dim3(16,16,16), 256, 0, stream>>>(hB, tB);

  for (int l = 0; l < 3; l++){
    float* sc = attn + (long)l*16*M1;
    // probs = softmax(h h^T / 32) -> d_out (fp32) + pB (bf16), fused
    attn_sm<<<256, 512, 0, stream>>>(hB, sc, pB);
    // ctx = P h   (B = h^T, K-contig)
    gemm8<1><<<256, 512, 0, stream>>>(pB, tB, 16, M1,M1,M1, 1024,1024,1024,
        1.f, nullptr, nullptr, nullptr, cB);
    // y1 = relu(ctx w1^T + b1)
    gemm8<2><<<256, 512, 0, stream>>>(cB, w1B+l*M1, 256, 0,0,0, 1024,1024,1024,
        1.f, b1+l*1024, nullptr, nullptr, pB);
    // rf = y1 w2^T + b2 + ctx
    gemm8<3><<<256, 512, 0, stream>>>(pB, w2B+l*M1, 256, 0,0,0, 1024,1024,1024,
        1.f, b2+l*1024, cB, rf, nullptr);
    // h = LN(rf)*g + b
    k_ln<<<16384, 256, 0, stream>>>(rf, lng+l*1024, lnb+l*1024, hB);
    if (l < 2) k_transpose<<<dim3(16,16,16), 256, 0, stream>>>(hB, tB);
  }

  k_final1<<<4096, 256, 0, stream>>>(hB, fcw, fcb, z);
  k_final2<<<96, 256, 0, stream>>>(z, fw, fb, out);
}